// Round 1
// baseline (372.314 us; speedup 1.0000x reference)
//
#include <hip/hip_runtime.h>

#define BB 8
#define CC 128
#define HH 64
#define WW 64
#define OO 128
#define KK9 9
#define NJ 18   // 2*K*K offset channels

// ---------------------------------------------------------------------------
// k0: transpose w_def (O,C,3,3) -> wdefT (kk, c, o) so GEMM staging is
// coalesced float4 in o.
// ---------------------------------------------------------------------------
__global__ void k_transpose_wdef(const float* __restrict__ w_def,
                                 float* __restrict__ wdefT) {
    int idx = blockIdx.x * 256 + threadIdx.x;   // 9*128*128 = 147456 total
    if (idx >= KK9 * CC * OO) return;
    int o  = idx & (OO - 1);
    int c  = (idx >> 7) & (CC - 1);
    int kk = idx >> 14;                          // / (C*O)
    wdefT[idx] = w_def[(o * CC + c) * KK9 + kk];
}

// ---------------------------------------------------------------------------
// k1: offset conv (3x3, pad 1). One thread per (b,h,w) computes all 18
// channels; c-range split in half across blocks for occupancy. Partial sums
// land in offs_part[half][b][j][h][w]; k2 adds the two halves.
// w_off addresses are wave-uniform -> scalar loads.
// ---------------------------------------------------------------------------
__global__ void k_offsets(const float* __restrict__ x,
                          const float* __restrict__ w_off,
                          const float* __restrict__ b_off,
                          float* __restrict__ offs_part) {
    int gid  = blockIdx.x * 256 + threadIdx.x;   // [0, 65536)
    int half = gid >> 15;                        // uniform per block
    int sp   = gid & 32767;
    int b = sp >> 12;
    int h = (sp >> 6) & 63;
    int w = sp & 63;

    float acc[NJ];
#pragma unroll
    for (int j = 0; j < NJ; ++j) acc[j] = (half == 0) ? b_off[j] : 0.0f;

    int c0 = half * (CC / 2);
    for (int c = c0; c < c0 + CC / 2; ++c) {
        const float* xc = x + (b * CC + c) * HH * WW;
        float p[9];
#pragma unroll
        for (int ky = 0; ky < 3; ++ky) {
            int y = h - 1 + ky;
#pragma unroll
            for (int kx = 0; kx < 3; ++kx) {
                int xx = w - 1 + kx;
                bool v = (y >= 0) && (y < HH) && (xx >= 0) && (xx < WW);
                p[ky * 3 + kx] = v ? xc[y * WW + xx] : 0.0f;
            }
        }
        const float* wo = w_off + c * KK9;       // [j][c][q] stride j: CC*9
#pragma unroll
        for (int j = 0; j < NJ; ++j) {
            const float* wj = wo + j * CC * KK9;
#pragma unroll
            for (int q = 0; q < 9; ++q) acc[j] += p[q] * wj[q];
        }
    }

#pragma unroll
    for (int j = 0; j < NJ; ++j) {
        offs_part[(((half * BB + b) * NJ + j) * HH + h) * WW + w] = acc[j];
    }
}

// ---------------------------------------------------------------------------
// k2: fused bilinear sample + (O x CKK) x (CKK x pos) contraction.
// Block: one (b, h, 32-wide w tile); 256 threads; each thread owns a
// 4(o) x 4(pos) fp32 accumulator tile. Per (kk, ctile of 16):
//   - coords (iy0,ix0,wy,wx) per pos in LDS (computed once per kk)
//   - samples s_samp[16c][32pos] in LDS (4 gathers + lerp each)
//   - weights s_wdef[16c][128o] in LDS (coalesced float4 from wdefT)
//   - inner: 16c x (2 ds_read_b128 + 16 v_fma) per thread
// ---------------------------------------------------------------------------
__global__ __launch_bounds__(256, 4)
void k_main(const float* __restrict__ x,
            const float* __restrict__ offs_part,
            const float* __restrict__ wdefT,
            const float* __restrict__ b_def,
            float* __restrict__ out) {
    __shared__ float s_samp[16][32];
    __shared__ float s_wdef[16][128];
    __shared__ int   s_iy0[32];
    __shared__ int   s_ix0[32];
    __shared__ float s_wy[32];
    __shared__ float s_wx[32];

    const int t = threadIdx.x;
    const int pos_grp = t & 7;    // 8 groups x 4 pos = 32 positions
    const int o_grp   = t >> 3;   // 32 groups x 4 o   = 128 outputs

    const int b   = blockIdx.x >> 7;
    const int rem = blockIdx.x & 127;
    const int h   = rem >> 1;
    const int w0  = (rem & 1) << 5;

    float acc[4][4];
#pragma unroll
    for (int i = 0; i < 4; ++i)
#pragma unroll
        for (int j = 0; j < 4; ++j) acc[i][j] = 0.0f;

    const int HALF = BB * NJ * HH * WW;   // offset between c-half partials

    for (int kk = 0; kk < 9; ++kk) {
        const int ky = kk / 3;
        const int kx = kk - ky * 3;
        if (t < 32) {
            int w = w0 + t;
            int base_y = ((b * NJ + 2 * kk) * HH + h) * WW + w;
            int base_x = ((b * NJ + 2 * kk + 1) * HH + h) * WW + w;
            float oy = offs_part[base_y] + offs_part[HALF + base_y];
            float ox = offs_part[base_x] + offs_part[HALF + base_x];
            float py = (float)(h - 1 + ky) + oy;
            float px = (float)(w - 1 + kx) + ox;
            float fy = floorf(py);
            float fx = floorf(px);
            s_iy0[t] = (int)fy;
            s_ix0[t] = (int)fx;
            s_wy[t]  = py - fy;
            s_wx[t]  = px - fx;
        }
        __syncthreads();

        for (int ct = 0; ct < 8; ++ct) {
            // ---- stage bilinear samples (2 per thread) ----
#pragma unroll
            for (int r = 0; r < 2; ++r) {
                int item = t + r * 256;
                int cl   = item >> 5;        // 0..15
                int pos  = item & 31;
                int c    = ct * 16 + cl;
                int iy0 = s_iy0[pos], ix0 = s_ix0[pos];
                float wy = s_wy[pos], wx = s_wx[pos];
                int iy1 = iy0 + 1, ix1 = ix0 + 1;
                int iy0c = min(max(iy0, 0), HH - 1);
                int iy1c = min(max(iy1, 0), HH - 1);
                int ix0c = min(max(ix0, 0), WW - 1);
                int ix1c = min(max(ix1, 0), WW - 1);
                float vy0 = (iy0 >= 0 && iy0 < HH) ? 1.0f : 0.0f;
                float vy1 = (iy1 >= 0 && iy1 < HH) ? 1.0f : 0.0f;
                float vx0 = (ix0 >= 0 && ix0 < WW) ? 1.0f : 0.0f;
                float vx1 = (ix1 >= 0 && ix1 < WW) ? 1.0f : 0.0f;
                const float* xc = x + (b * CC + c) * HH * WW;
                float v00 = xc[iy0c * WW + ix0c] * (vy0 * vx0);
                float v01 = xc[iy0c * WW + ix1c] * (vy0 * vx1);
                float v10 = xc[iy1c * WW + ix0c] * (vy1 * vx0);
                float v11 = xc[iy1c * WW + ix1c] * (vy1 * vx1);
                float top = v00 + wx * (v01 - v00);
                float bot = v10 + wx * (v11 - v10);
                s_samp[cl][pos] = top + wy * (bot - top);
            }
            // ---- stage weight tile (2 float4 per thread) ----
#pragma unroll
            for (int r = 0; r < 2; ++r) {
                int idx = t + r * 256;
                int cl  = idx >> 5;          // 0..15
                int o4  = idx & 31;
                int c   = ct * 16 + cl;
                const float4 wv =
                    *(const float4*)(wdefT + (kk * CC + c) * OO + o4 * 4);
                *(float4*)&s_wdef[cl][o4 * 4] = wv;
            }
            __syncthreads();

            // ---- 4x4 register-tile FMA over 16 c ----
#pragma unroll
            for (int cl = 0; cl < 16; ++cl) {
                float4 sv = *(const float4*)&s_samp[cl][pos_grp * 4];
                float4 wv = *(const float4*)&s_wdef[cl][o_grp * 4];
                float svv[4] = {sv.x, sv.y, sv.z, sv.w};
                float wvv[4] = {wv.x, wv.y, wv.z, wv.w};
#pragma unroll
                for (int i = 0; i < 4; ++i)
#pragma unroll
                    for (int j = 0; j < 4; ++j)
                        acc[i][j] += wvv[i] * svv[j];
            }
            __syncthreads();
        }
    }

    // ---- epilogue: + b_def, coalesced float4 stores ----
    const float4 bv = *(const float4*)(b_def + o_grp * 4);
    float bvv[4] = {bv.x, bv.y, bv.z, bv.w};
#pragma unroll
    for (int i = 0; i < 4; ++i) {
        int o = o_grp * 4 + i;
        float4 res;
        res.x = acc[i][0] + bvv[i];
        res.y = acc[i][1] + bvv[i];
        res.z = acc[i][2] + bvv[i];
        res.w = acc[i][3] + bvv[i];
        *(float4*)(out + ((b * OO + o) * HH + h) * WW + w0 + pos_grp * 4) = res;
    }
}

extern "C" void kernel_launch(void* const* d_in, const int* in_sizes, int n_in,
                              void* d_out, int out_size, void* d_ws, size_t ws_size,
                              hipStream_t stream) {
    const float* x     = (const float*)d_in[0];
    const float* w_off = (const float*)d_in[1];
    const float* b_off = (const float*)d_in[2];
    const float* w_def = (const float*)d_in[3];
    const float* b_def = (const float*)d_in[4];
    float* out = (float*)d_out;

    // workspace layout: offs_part (2 halves) | wdefT
    float* offs_part = (float*)d_ws;                       // 2*8*18*64*64 = 1179648 f
    float* wdefT     = offs_part + 2 * BB * NJ * HH * WW;  // 147456 f

    k_transpose_wdef<<<(KK9 * CC * OO + 255) / 256, 256, 0, stream>>>(w_def, wdefT);
    k_offsets<<<256, 256, 0, stream>>>(x, w_off, b_off, offs_part);
    k_main<<<BB * HH * 2, 256, 0, stream>>>(x, offs_part, wdefT, b_def, out);
}

// Round 2
// 241.461 us; speedup vs baseline: 1.5419x; 1.5419x over previous
//
#include <hip/hip_runtime.h>

#define BB 8
#define CC 128
#define HH 64
#define WW 64
#define OO 128
#define NJ 18
#define HW 4096            // 64*64
#define HALF (BB*NJ*HW)    // offset between c-half partials

typedef unsigned short u16;
typedef unsigned int u32;
typedef __attribute__((ext_vector_type(8))) __bf16 bf16x8;
typedef __attribute__((ext_vector_type(4))) float f32x4;

__device__ __forceinline__ u16 f2bf(float f) {
    u32 u = __float_as_uint(f);
    u += 0x7fffu + ((u >> 16) & 1u);   // RNE
    return (u16)(u >> 16);
}

// ---------------------------------------------------------------------------
// k0: w_def (O,C,3,3) fp32 -> wT[kk][o][c] bf16 (c contiguous = MFMA A-frag
// order: each lane reads 8 consecutive c for fixed o).
// ---------------------------------------------------------------------------
__global__ void k_transpose_wdef(const float* __restrict__ w_def,
                                 u16* __restrict__ wT) {
    int idx = blockIdx.x * 256 + threadIdx.x;     // kk*16384 + o*128 + c
    if (idx >= 9 * OO * CC) return;
    int c  = idx & 127;
    int o  = (idx >> 7) & 127;
    int kk = idx >> 14;
    wT[idx] = f2bf(w_def[(o * CC + c) * 9 + kk]);
}

// ---------------------------------------------------------------------------
// k1: offset conv, fp32 (coordinates must stay exact-ish).
// Grid 512 = 128 spatial x 2 jhalf x 2 chalf -> 2 blocks/CU, 2 waves/SIMD.
// w_off quarter staged in LDS, rows padded to 16 floats for aligned float4
// broadcast reads. Partials: offs_part[chalf][b][j][h][w].
// ---------------------------------------------------------------------------
__global__ __launch_bounds__(256)
void k_offsets(const float* __restrict__ x,
               const float* __restrict__ w_off,
               const float* __restrict__ b_off,
               float* __restrict__ offs_part) {
    __shared__ float s_w[64][9][16];   // [cl][jl][q padded] = 36864 B

    const int t    = threadIdx.x;
    const int bid  = blockIdx.x;
    const int spat  = bid & 127;
    const int jhalf = (bid >> 7) & 1;
    const int chalf = bid >> 8;
    const int c0 = chalf * 64;
    const int j0 = jhalf * 9;

    for (int i = t; i < 64 * 81; i += 256) {
        int cl = i / 81;
        int r  = i - cl * 81;
        int jl = r / 9;
        int q  = r - jl * 9;
        s_w[cl][jl][q] = w_off[((j0 + jl) * CC + c0 + cl) * 9 + q];
    }
    __syncthreads();

    const int sp = spat * 256 + t;
    const int b = sp >> 12;
    const int h = (sp >> 6) & 63;
    const int w = sp & 63;

    float acc[9];
#pragma unroll
    for (int jl = 0; jl < 9; ++jl)
        acc[jl] = (chalf == 0) ? b_off[j0 + jl] : 0.0f;

    for (int cl = 0; cl < 64; ++cl) {
        const float* xc = x + (b * CC + c0 + cl) * HW;
        float p[9];
#pragma unroll
        for (int ky = 0; ky < 3; ++ky) {
            int y = h - 1 + ky;
#pragma unroll
            for (int kx = 0; kx < 3; ++kx) {
                int xx = w - 1 + kx;
                bool v = (y >= 0) && (y < HH) && (xx >= 0) && (xx < WW);
                p[ky * 3 + kx] = v ? xc[y * WW + xx] : 0.0f;
            }
        }
#pragma unroll
        for (int jl = 0; jl < 9; ++jl) {
            float4 wa = *(const float4*)&s_w[cl][jl][0];
            float4 wb = *(const float4*)&s_w[cl][jl][4];
            float  w8 = s_w[cl][jl][8];
            acc[jl] += p[0]*wa.x + p[1]*wa.y + p[2]*wa.z + p[3]*wa.w
                     + p[4]*wb.x + p[5]*wb.y + p[6]*wb.z + p[7]*wb.w
                     + p[8]*w8;
        }
    }

#pragma unroll
    for (int jl = 0; jl < 9; ++jl)
        offs_part[((chalf * BB + b) * NJ + j0 + jl) * HW + h * WW + w] = acc[jl];
}

// ---------------------------------------------------------------------------
// k2: fused bilinear sample + bf16 MFMA GEMM.
// Block = (b, h row): 64 pos x 128 o, 256 threads (4 waves).
// Wave wv owns n-tile wv (16 pos), all 8 m-tiles (16 o each).
// Per kk: stage w slice [128o][128c+8pad] bf16 (34816 B), coords for 64 pos.
// Per 32-c K-step: stage samp [64pos][32c+8pad] bf16, then 8x
// mfma_f32_16x16x32_bf16 per wave.
// ---------------------------------------------------------------------------
__global__ __launch_bounds__(256, 2)
void k_main(const float* __restrict__ x,
            const float* __restrict__ offs_part,
            const u16* __restrict__ wT,
            const float* __restrict__ b_def,
            float* __restrict__ out) {
    __shared__ u16    s_wt[128 * 136];   // [o][c] pad 8 -> 34816 B
    __shared__ u16    s_samp[64 * 40];   // [pos][c] pad 8 -> 5120 B
    __shared__ float4 s_cw[64];          // per-corner weights (validity folded)
    __shared__ int4   s_co[64];          // clamped element offsets in plane

    const int t    = threadIdx.x;
    const int lane = t & 63;
    const int wv   = t >> 6;
    const int b = blockIdx.x >> 6;
    const int h = blockIdx.x & 63;
    const float* xb = x + b * CC * HW;

    f32x4 acc[8];
#pragma unroll
    for (int mt = 0; mt < 8; ++mt) acc[mt] = (f32x4)0.0f;

    for (int kk = 0; kk < 9; ++kk) {
        // ---- stage weight slice (coalesced uint4) ----
#pragma unroll
        for (int r = 0; r < 8; ++r) {
            int item = r * 256 + t;            // 2048 x 16B = 32 KB
            int o    = item >> 4;
            int seg  = item & 15;
            *(uint4*)&s_wt[o * 136 + seg * 8] =
                *(const uint4*)&wT[kk * (OO * CC) + item * 8];
        }
        // ---- coords for 64 positions ----
        if (t < 64) {
            int w  = t;
            int ky = kk / 3;
            int kx = kk - ky * 3;
            int idy = ((b * NJ + 2 * kk) * HH + h) * WW + w;
            float oy = offs_part[idy] + offs_part[HALF + idy];
            float ox = offs_part[idy + HW] + offs_part[HALF + idy + HW];
            float py = (float)(h - 1 + ky) + oy;
            float px = (float)(w - 1 + kx) + ox;
            float fy = floorf(py), fx = floorf(px);
            int iy0 = (int)fy, ix0 = (int)fx;
            float wy = py - fy, wx = px - fx;
            int iy1 = iy0 + 1, ix1 = ix0 + 1;
            float my0 = (iy0 >= 0 && iy0 < HH) ? 1.0f : 0.0f;
            float my1 = (iy1 >= 0 && iy1 < HH) ? 1.0f : 0.0f;
            float mx0 = (ix0 >= 0 && ix0 < WW) ? 1.0f : 0.0f;
            float mx1 = (ix1 >= 0 && ix1 < WW) ? 1.0f : 0.0f;
            int iy0c = min(max(iy0, 0), HH - 1), iy1c = min(max(iy1, 0), HH - 1);
            int ix0c = min(max(ix0, 0), WW - 1), ix1c = min(max(ix1, 0), WW - 1);
            float wy1 = 1.0f - wy, wx1 = 1.0f - wx;
            s_cw[w] = make_float4(my0 * mx0 * wy1 * wx1, my0 * mx1 * wy1 * wx,
                                  my1 * mx0 * wy  * wx1, my1 * mx1 * wy  * wx);
            s_co[w] = make_int4(iy0c * WW + ix0c, iy0c * WW + ix1c,
                                iy1c * WW + ix0c, iy1c * WW + ix1c);
        }
        __syncthreads();

        const int pos  = lane;     // staging role: 64 pos x 4 c-subgroups
        const int csub = wv;
        const float4 cw = s_cw[pos];
        const int4   co = s_co[pos];

        for (int ct = 0; ct < 4; ++ct) {
            // ---- stage 8 bilinear samples -> one b128 LDS write ----
            union { u16 u[8]; uint4 v; } tmp;
#pragma unroll
            for (int i = 0; i < 8; ++i) {
                int c  = ct * 32 + csub * 8 + i;
                int cb = c << 12;              // c * 4096 elements
                float v00 = xb[cb + co.x];
                float v01 = xb[cb + co.y];
                float v10 = xb[cb + co.z];
                float v11 = xb[cb + co.w];
                float s = cw.x * v00 + cw.y * v01 + cw.z * v10 + cw.w * v11;
                tmp.u[i] = f2bf(s);
            }
            *(uint4*)&s_samp[pos * 40 + csub * 8] = tmp.v;
            __syncthreads();

            // ---- MFMA: B-frag = samples (n=pos), A-frags = weights (m=o) ----
            bf16x8 bfrag = *(const bf16x8*)
                &s_samp[(wv * 16 + (lane & 15)) * 40 + (lane >> 4) * 8];
            const int aoff = ct * 32 + (lane >> 4) * 8;
#pragma unroll
            for (int mt = 0; mt < 8; ++mt) {
                bf16x8 afrag = *(const bf16x8*)
                    &s_wt[(mt * 16 + (lane & 15)) * 136 + aoff];
                acc[mt] = __builtin_amdgcn_mfma_f32_16x16x32_bf16(
                    afrag, bfrag, acc[mt], 0, 0, 0);
            }
            __syncthreads();
        }
    }

    // ---- epilogue: D row = o = mt*16 + (lane>>4)*4 + reg, col = pos ----
    const int pos   = wv * 16 + (lane & 15);
    const int orow0 = (lane >> 4) * 4;
#pragma unroll
    for (int mt = 0; mt < 8; ++mt) {
#pragma unroll
        for (int r = 0; r < 4; ++r) {
            int o = mt * 16 + orow0 + r;
            out[((b * OO + o) * HH + h) * WW + pos] = acc[mt][r] + b_def[o];
        }
    }
}

extern "C" void kernel_launch(void* const* d_in, const int* in_sizes, int n_in,
                              void* d_out, int out_size, void* d_ws, size_t ws_size,
                              hipStream_t stream) {
    const float* x     = (const float*)d_in[0];
    const float* w_off = (const float*)d_in[1];
    const float* b_off = (const float*)d_in[2];
    const float* w_def = (const float*)d_in[3];
    const float* b_def = (const float*)d_in[4];
    float* out = (float*)d_out;

    float* offs_part = (float*)d_ws;                 // 2*8*18*4096 f = 4.72 MB
    u16*   wT        = (u16*)(offs_part + 2 * HALF); // 147456 bf16 = 0.29 MB

    k_transpose_wdef<<<(9 * OO * CC + 255) / 256, 256, 0, stream>>>(w_def, wT);
    k_offsets<<<512, 256, 0, stream>>>(x, w_off, b_off, offs_part);
    k_main<<<BB * HH, 256, 0, stream>>>(x, offs_part, wT, b_def, out);
}

// Round 3
// 139.438 us; speedup vs baseline: 2.6701x; 1.7317x over previous
//
#include <hip/hip_runtime.h>

#define BB 8
#define CC 128
#define HH 64
#define WW 64
#define OO 128
#define NJ 18
#define HW 4096

typedef unsigned short u16;
typedef unsigned int u32;
typedef __attribute__((ext_vector_type(8))) __bf16 bf16x8;
typedef __attribute__((ext_vector_type(4))) float f32x4;

__device__ __forceinline__ u16 f2bf(float f) {
    u32 u = __float_as_uint(f);
    u += 0x7fffu + ((u >> 16) & 1u);   // RNE
    return (u16)(u >> 16);
}
__device__ __forceinline__ float bflo(u32 u) { return __uint_as_float(u << 16); }
__device__ __forceinline__ float bfhi(u32 u) { return __uint_as_float(u & 0xffff0000u); }

// ---------------------------------------------------------------------------
// k_xT: x[b][c][hw] fp32 -> xT[b][hw][c] bf16 (channels-last). LDS tile
// transpose; block = (b, 64-hw tile).
// ---------------------------------------------------------------------------
__global__ __launch_bounds__(256)
void k_xT(const float* __restrict__ x, u16* __restrict__ xT) {
    __shared__ float tile[128][65];
    const int t = threadIdx.x;
    const int b = blockIdx.x >> 6;
    const int hw0 = (blockIdx.x & 63) << 6;
    const float* xb = x + (size_t)b * CC * HW + hw0;
    const int tw = t & 63, tc = t >> 6;
#pragma unroll
    for (int r = 0; r < 32; ++r) {
        int c = r * 4 + tc;
        tile[c][tw] = xb[c * HW + tw];
    }
    __syncthreads();
    const int seg = t & 15, hwl = t >> 4;
    u16* dst = xT + ((size_t)b * HW + hw0) * CC;
#pragma unroll
    for (int r = 0; r < 4; ++r) {
        int hw = hwl + r * 16;
        union { u16 u[8]; uint4 v; } p;
#pragma unroll
        for (int i = 0; i < 8; ++i) p.u[i] = f2bf(tile[seg * 8 + i][hw]);
        *(uint4*)&dst[hw * CC + seg * 8] = p.v;
    }
}

// ---------------------------------------------------------------------------
// k_prep: wT[kk][o][c] bf16 (main-conv A operand) and wA[j][q*128+c] bf16
// (offset-conv A operand, j padded to 32 with ZEROS).
// ---------------------------------------------------------------------------
__global__ void k_prep(const float* __restrict__ w_def,
                       const float* __restrict__ w_off,
                       u16* __restrict__ wT, u16* __restrict__ wA) {
    int idx = blockIdx.x * 256 + threadIdx.x;
    if (idx < 9 * OO * CC) {
        int c = idx & 127, o = (idx >> 7) & 127, kk = idx >> 14;
        wT[idx] = f2bf(w_def[(o * CC + c) * 9 + kk]);
    }
    if (idx < 32 * 1152) {
        int k = idx % 1152, j = idx / 1152;
        int q = k >> 7, c = k & 127;
        wA[idx] = (j < NJ) ? f2bf(w_off[(j * CC + c) * 9 + q]) : (u16)0;
    }
}

// ---------------------------------------------------------------------------
// k_off: offset conv via MFMA. Block = (b, h): M=18(->32), N=64, K=1152
// (k = q*128 + c). Stage 3 halo rows of xT (zero-filled OOB) in XOR-swizzled
// LDS; B-frags are contiguous-c reads at fixed q. A-frags straight from
// global (72 KB, L1/L2-hot). Output offs[b][j][hw] fp32 + b_off.
// ---------------------------------------------------------------------------
__global__ __launch_bounds__(256, 2)
void k_off(const u16* __restrict__ xT, const u16* __restrict__ wA,
           const float* __restrict__ b_off, float* __restrict__ offs) {
    __shared__ u16 s_x[198 * 128];   // [3 rows x 66 w][128 c] swizzled, 50688 B
    const int t = threadIdx.x, lane = t & 63, wv = t >> 6;
    const int posl = lane & 15, kg = lane >> 4;
    const int b = blockIdx.x >> 6, h = blockIdx.x & 63;

    for (int it = t; it < 3168; it += 256) {
        int seg = it & 15, pix = it >> 4;       // pix = r*66 + wp
        int r = pix / 66, wp = pix - r * 66;
        int y = h - 1 + r, w = wp - 1;
        uint4 v = make_uint4(0, 0, 0, 0);
        if (y >= 0 && y < HH && w >= 0 && w < WW)
            v = *(const uint4*)&xT[((size_t)(b * HW) + y * WW + w) * CC + seg * 8];
        *(uint4*)&s_x[pix * 128 + ((seg ^ (pix & 15)) * 8)] = v;
    }
    __syncthreads();

    f32x4 acc0 = {0.f, 0.f, 0.f, 0.f}, acc1 = {0.f, 0.f, 0.f, 0.f};
    for (int q = 0; q < 9; ++q) {
        int qy = q / 3, qx = q - qy * 3;
        int pix = qy * 66 + (wv * 16 + posl) + qx;
        int prow = pix * 128, pxor = pix & 15;
#pragma unroll
        for (int ki = 0; ki < 4; ++ki) {
            int ks = q * 4 + ki;
            int cidx = ki * 4 + kg;
            bf16x8 bfr = *(const bf16x8*)&s_x[prow + ((cidx ^ pxor) * 8)];
            bf16x8 a0 = *(const bf16x8*)&wA[posl * 1152 + ks * 32 + kg * 8];
            bf16x8 a1 = *(const bf16x8*)&wA[(16 + posl) * 1152 + ks * 32 + kg * 8];
            acc0 = __builtin_amdgcn_mfma_f32_16x16x32_bf16(a0, bfr, acc0, 0, 0, 0);
            acc1 = __builtin_amdgcn_mfma_f32_16x16x32_bf16(a1, bfr, acc1, 0, 0, 0);
        }
    }
    const int pos = wv * 16 + posl;
#pragma unroll
    for (int r = 0; r < 4; ++r) {
        int j = kg * 4 + r;
        offs[(b * NJ + j) * HW + h * WW + pos] = acc0[r] + b_off[j];
    }
#pragma unroll
    for (int r = 0; r < 4; ++r) {
        int j = 16 + kg * 4 + r;
        if (j < NJ) offs[(b * NJ + j) * HW + h * WW + pos] = acc1[r] + b_off[j];
    }
}

// ---------------------------------------------------------------------------
// k_main: fused bilinear sample + bf16 MFMA GEMM, channels-last gathers.
// Block = (b, h-pair): N=128 pos, M=128 o, 256 threads / 4 waves.
// Per kk: coords(128) | stage wT slice + 1024 corner-vector gathers
// (coalesced uint4) + fp32 interp -> bf16 LDS | 32 MFMAs. XOR-swizzled LDS.
// Wave wv: ntiles {2wv, 2wv+1} x all 8 mtiles.
// ---------------------------------------------------------------------------
__global__ __launch_bounds__(256, 2)
void k_main(const u16* __restrict__ xT, const float* __restrict__ offs,
            const u16* __restrict__ wT, const float* __restrict__ b_def,
            float* __restrict__ out) {
    __shared__ u16    s_wt[128 * 128];    // 32 KB, swizzled [o][c]
    __shared__ u16    s_samp[128 * 128];  // 32 KB, swizzled [pos][c]
    __shared__ float4 s_cw[128];
    __shared__ int4   s_co[128];          // corner BYTE offsets into b-plane

    const int t = threadIdx.x, lane = t & 63, wv = t >> 6;
    const int posl = lane & 15, rg = lane >> 4;
    const int b = blockIdx.x >> 5;
    const int h0 = (blockIdx.x & 31) << 1;
    const char* xb = (const char*)xT + (size_t)b * (HW * CC * 2);

    f32x4 acc[8][2];
#pragma unroll
    for (int mt = 0; mt < 8; ++mt) {
        acc[mt][0] = (f32x4){0.f, 0.f, 0.f, 0.f};
        acc[mt][1] = (f32x4){0.f, 0.f, 0.f, 0.f};
    }

    for (int kk = 0; kk < 9; ++kk) {
        // ---- coords for 128 positions (2 rows x 64 w) ----
        if (t < 128) {
            int w = t & 63, hc = h0 + (t >> 6);
            int ky = kk / 3, kx = kk - ky * 3;
            int idy = (b * NJ + 2 * kk) * HW + hc * WW + w;
            float oy = offs[idy];
            float ox = offs[idy + HW];
            float py = (float)(hc - 1 + ky) + oy;
            float px = (float)(w - 1 + kx) + ox;
            float fy = floorf(py), fx = floorf(px);
            int iy0 = (int)fy, ix0 = (int)fx;
            float wy = py - fy, wx = px - fx;
            int iy1 = iy0 + 1, ix1 = ix0 + 1;
            float my0 = (iy0 >= 0 && iy0 < HH) ? 1.0f : 0.0f;
            float my1 = (iy1 >= 0 && iy1 < HH) ? 1.0f : 0.0f;
            float mx0 = (ix0 >= 0 && ix0 < WW) ? 1.0f : 0.0f;
            float mx1 = (ix1 >= 0 && ix1 < WW) ? 1.0f : 0.0f;
            int iy0c = min(max(iy0, 0), HH - 1), iy1c = min(max(iy1, 0), HH - 1);
            int ix0c = min(max(ix0, 0), WW - 1), ix1c = min(max(ix1, 0), WW - 1);
            float wy1 = 1.0f - wy, wx1 = 1.0f - wx;
            s_cw[t] = make_float4(my0 * mx0 * wy1 * wx1, my0 * mx1 * wy1 * wx,
                                  my1 * mx0 * wy  * wx1, my1 * mx1 * wy  * wx);
            s_co[t] = make_int4((iy0c * WW + ix0c) << 8, (iy0c * WW + ix1c) << 8,
                                (iy1c * WW + ix0c) << 8, (iy1c * WW + ix1c) << 8);
        }
        __syncthreads();

        // ---- stage weight slice (coalesced uint4 -> swizzled LDS) ----
#pragma unroll
        for (int r = 0; r < 8; ++r) {
            int item = r * 256 + t;
            int o = item >> 4, sg = item & 15;
            *(uint4*)&s_wt[o * 128 + ((sg ^ (o & 15)) * 8)] =
                *(const uint4*)&wT[kk * (OO * CC) + item * 8];
        }
        // ---- gather + interp: 128 pos x 16 segs, 8 items/thread ----
        {
            const int sg = t & 15;
            const char* base = xb + sg * 16;
#pragma unroll
            for (int r = 0; r < 8; ++r) {
                int pos = (t >> 4) + r * 16;
                float4 cw = s_cw[pos];
                int4 co = s_co[pos];
                uint4 q00 = *(const uint4*)(base + co.x);
                uint4 q01 = *(const uint4*)(base + co.y);
                uint4 q10 = *(const uint4*)(base + co.z);
                uint4 q11 = *(const uint4*)(base + co.w);
                const u32* u00 = (const u32*)&q00;
                const u32* u01 = (const u32*)&q01;
                const u32* u10 = (const u32*)&q10;
                const u32* u11 = (const u32*)&q11;
                union { u16 u[8]; uint4 v; } p;
#pragma unroll
                for (int i = 0; i < 4; ++i) {
                    float s0 = cw.x * bflo(u00[i]) + cw.y * bflo(u01[i])
                             + cw.z * bflo(u10[i]) + cw.w * bflo(u11[i]);
                    float s1 = cw.x * bfhi(u00[i]) + cw.y * bfhi(u01[i])
                             + cw.z * bfhi(u10[i]) + cw.w * bfhi(u11[i]);
                    p.u[2 * i]     = f2bf(s0);
                    p.u[2 * i + 1] = f2bf(s1);
                }
                *(uint4*)&s_samp[pos * 128 + ((sg ^ (pos & 15)) * 8)] = p.v;
            }
        }
        __syncthreads();

        // ---- 32 MFMAs: 4 ksteps x 8 mtiles x 2 ntiles ----
#pragma unroll
        for (int ct = 0; ct < 4; ++ct) {
            const int cidx = ct * 4 + rg;
            const int sw = (cidx ^ posl) * 8;
            bf16x8 bf0 = *(const bf16x8*)&s_samp[(2 * wv * 16 + posl) * 128 + sw];
            bf16x8 bf1 = *(const bf16x8*)&s_samp[((2 * wv + 1) * 16 + posl) * 128 + sw];
#pragma unroll
            for (int mt = 0; mt < 8; ++mt) {
                bf16x8 af = *(const bf16x8*)&s_wt[(mt * 16 + posl) * 128 + sw];
                acc[mt][0] = __builtin_amdgcn_mfma_f32_16x16x32_bf16(af, bf0, acc[mt][0], 0, 0, 0);
                acc[mt][1] = __builtin_amdgcn_mfma_f32_16x16x32_bf16(af, bf1, acc[mt][1], 0, 0, 0);
            }
        }
        __syncthreads();
    }

    // ---- epilogue ----
#pragma unroll
    for (int mt = 0; mt < 8; ++mt) {
#pragma unroll
        for (int j = 0; j < 2; ++j) {
            int pos = (2 * wv + j) * 16 + posl;
            int h = h0 + (pos >> 6), w = pos & 63;
#pragma unroll
            for (int r = 0; r < 4; ++r) {
                int o = mt * 16 + rg * 4 + r;
                out[((b * OO + o) * HH + h) * WW + w] = acc[mt][j][r] + b_def[o];
            }
        }
    }
}

extern "C" void kernel_launch(void* const* d_in, const int* in_sizes, int n_in,
                              void* d_out, int out_size, void* d_ws, size_t ws_size,
                              hipStream_t stream) {
    const float* x     = (const float*)d_in[0];
    const float* w_off = (const float*)d_in[1];
    const float* b_off = (const float*)d_in[2];
    const float* w_def = (const float*)d_in[3];
    const float* b_def = (const float*)d_in[4];
    float* out = (float*)d_out;

    // ws layout (11.1 MB): offs fp32 | xT bf16 | wT bf16 | wA bf16
    float* offs = (float*)d_ws;                  // 8*18*4096 f   = 2.36 MB
    u16*   xT   = (u16*)(offs + BB * NJ * HW);   // 8*4096*128    = 8.39 MB
    u16*   wT   = xT + (size_t)BB * HW * CC;     // 9*128*128     = 0.29 MB
    u16*   wA   = wT + 9 * OO * CC;              // 32*1152       = 0.07 MB

    k_xT  <<<512, 256, 0, stream>>>(x, xT);
    k_prep<<<576, 256, 0, stream>>>(w_def, w_off, wT, wA);
    k_off <<<512, 256, 0, stream>>>(xT, wA, b_off, offs);
    k_main<<<256, 256, 0, stream>>>(xT, offs, wT, b_def, out);
}